// Round 2
// baseline (631.292 us; speedup 1.0000x reference)
//
#include <hip/hip_runtime.h>
#include <stdint.h>

#define B_   8
#define T_   4096
#define DIN  1330
#define DH   64
#define DC   16
#define KK   2
#define M_   (B_*T_)       // 32768
#define DINP 1344          // 42*32, zero-padded K for W1^T

// ---- workspace layout (floats) ----
#define OFF_W1T 0
#define OFF_H1  (DINP*DH)                 // 86016
#define OFF_EM  (OFF_H1 + M_*DH)          // + 2097152
#define WS_FLOATS (OFF_EM + M_*KK)

// ------------------------------------------------------------------
// K0: W1 (64 x 1330) -> W1T (1344 x 64), zero-padded rows >= 1330
// ------------------------------------------------------------------
__global__ void k_transpose_w1(const float* __restrict__ W1, float* __restrict__ w1t) {
    int idx = blockIdx.x * 256 + threadIdx.x;
    if (idx >= DINP * DH) return;
    int d = idx >> 6, h = idx & 63;
    w1t[idx] = (d < DIN) ? W1[h * DIN + d] : 0.f;
}

// ------------------------------------------------------------------
// K1: h1 = relu(x @ W1^T + b1)   (32768 x 1330) x (1330 x 64)
// 64-row tile / block, 256 threads, K-chunk 32.
// A in LDS: k-major-readable swizzled layout, slot(m,k) = m*36 + 4*((k>>2)^((m>>3)&7)) + (k&3)
// B in LDS: [k][64] linear.
// ------------------------------------------------------------------
#define MT 64
#define KC 32
__global__ __launch_bounds__(256) void k_gemm1(const float* __restrict__ x,
                                               const float* __restrict__ w1t,
                                               const float* __restrict__ b1,
                                               float* __restrict__ h1) {
    __shared__ float As[MT * 36];      // 9216 B
    __shared__ float Bs[KC * DH];      // 8192 B
    const int tid  = threadIdx.x;
    const int row0 = blockIdx.x * MT;
    const int jm = tid & 15, jh = tid >> 4;
    const int m0 = jm * 4, h0 = jh * 4;
    const int s_rd = jm >> 1;          // == ((m0+i)>>3)&7 for i in 0..3

    float4 acc[4];
#pragma unroll
    for (int i = 0; i < 4; ++i) acc[i] = make_float4(0.f, 0.f, 0.f, 0.f);

    const int NCH = DINP / KC;  // 42
    for (int ch = 0; ch < NCH; ++ch) {
        const int kc = ch * KC;
        // ---- stage B: Bs[k][h] = w1t[(kc+k)*64 + h], 2048 floats ----
#pragma unroll
        for (int it = 0; it < 2; ++it) {
            int p = it * 256 + tid;
            reinterpret_cast<float4*>(Bs)[p] =
                reinterpret_cast<const float4*>(w1t + (size_t)kc * DH)[p];
        }
        // ---- stage A (swizzled) ----
        if (ch < NCH - 1) {
#pragma unroll
            for (int it = 0; it < 4; ++it) {
                int P = it * 256 + tid;          // pair index [0,1024)
                int m = P >> 4, kp = P & 15;     // k = 2*kp
                float2 v = *reinterpret_cast<const float2*>(
                    x + (size_t)(row0 + m) * DIN + kc + kp * 2);
                int s = (m >> 3) & 7;
                int slot = m * 36 + 4 * ((kp >> 1) ^ s) + 2 * (kp & 1);
                *reinterpret_cast<float2*>(As + slot) = v;
            }
        } else {
            // tail: only k < 1330 valid, zero-fill the rest
            for (int idx = tid; idx < MT * KC; idx += 256) {
                int m = idx >> 5, k = idx & 31;
                float v = (kc + k < DIN) ? x[(size_t)(row0 + m) * DIN + kc + k] : 0.f;
                int s = (m >> 3) & 7;
                As[m * 36 + 4 * ((k >> 2) ^ s) + (k & 3)] = v;
            }
        }
        __syncthreads();
        // ---- compute ----
#pragma unroll
        for (int kq = 0; kq < 8; ++kq) {
            float4 bv0 = *reinterpret_cast<const float4*>(Bs + (kq * 4 + 0) * DH + h0);
            float4 bv1 = *reinterpret_cast<const float4*>(Bs + (kq * 4 + 1) * DH + h0);
            float4 bv2 = *reinterpret_cast<const float4*>(Bs + (kq * 4 + 2) * DH + h0);
            float4 bv3 = *reinterpret_cast<const float4*>(Bs + (kq * 4 + 3) * DH + h0);
            const int xo = 4 * (kq ^ s_rd);
#pragma unroll
            for (int i = 0; i < 4; ++i) {
                const float4 av = *reinterpret_cast<const float4*>(As + (m0 + i) * 36 + xo);
                acc[i].x = fmaf(av.x, bv0.x, acc[i].x);
                acc[i].y = fmaf(av.x, bv0.y, acc[i].y);
                acc[i].z = fmaf(av.x, bv0.z, acc[i].z);
                acc[i].w = fmaf(av.x, bv0.w, acc[i].w);
                acc[i].x = fmaf(av.y, bv1.x, acc[i].x);
                acc[i].y = fmaf(av.y, bv1.y, acc[i].y);
                acc[i].z = fmaf(av.y, bv1.z, acc[i].z);
                acc[i].w = fmaf(av.y, bv1.w, acc[i].w);
                acc[i].x = fmaf(av.z, bv2.x, acc[i].x);
                acc[i].y = fmaf(av.z, bv2.y, acc[i].y);
                acc[i].z = fmaf(av.z, bv2.z, acc[i].z);
                acc[i].w = fmaf(av.z, bv2.w, acc[i].w);
                acc[i].x = fmaf(av.w, bv3.x, acc[i].x);
                acc[i].y = fmaf(av.w, bv3.y, acc[i].y);
                acc[i].z = fmaf(av.w, bv3.z, acc[i].z);
                acc[i].w = fmaf(av.w, bv3.w, acc[i].w);
            }
        }
        __syncthreads();
    }
    // epilogue: + b1, relu, store
    float4 bb = *reinterpret_cast<const float4*>(b1 + h0);
#pragma unroll
    for (int i = 0; i < 4; ++i) {
        float4 o;
        o.x = fmaxf(acc[i].x + bb.x, 0.f);
        o.y = fmaxf(acc[i].y + bb.y, 0.f);
        o.z = fmaxf(acc[i].z + bb.z, 0.f);
        o.w = fmaxf(acc[i].w + bb.w, 0.f);
        *reinterpret_cast<float4*>(h1 + (size_t)(row0 + m0 + i) * DH + h0) = o;
    }
}

// ------------------------------------------------------------------
// K2: em = relu(conv1d(h1, Wc, pad=1) + bc) @ W2^T + b2
// one thread per token; Wc reorganized [w][h][c] in LDS.
// Also zeroes outp[0] so the CRF kernel can atomicAdd into it.
// ------------------------------------------------------------------
__global__ __launch_bounds__(256) void k_conv_em(const float* __restrict__ h1,
                                                 const float* __restrict__ Wc,
                                                 const float* __restrict__ bc,
                                                 const float* __restrict__ W2,
                                                 const float* __restrict__ b2,
                                                 float* __restrict__ em,
                                                 float* __restrict__ outp) {
    __shared__ float kk[3 * DH * DC];  // 12 KB: kk[w][h][c] = Wc[c][h][w]
    int tid = threadIdx.x;
    if (blockIdx.x == 0 && tid == 0) outp[0] = 0.f;
    for (int idx = tid; idx < 3 * DH * DC; idx += 256) {
        int w = idx / (DH * DC);
        int rem = idx - w * DH * DC;
        int h = rem >> 4, c = rem & 15;
        kk[idx] = Wc[(c * DH + h) * 3 + w];
    }
    __syncthreads();
    int tglob = blockIdx.x * 256 + tid;   // [0, 32768)
    int b = tglob >> 12, tt = tglob & 4095;

    float4 acc0 = *reinterpret_cast<const float4*>(bc + 0);
    float4 acc1 = *reinterpret_cast<const float4*>(bc + 4);
    float4 acc2 = *reinterpret_cast<const float4*>(bc + 8);
    float4 acc3 = *reinterpret_cast<const float4*>(bc + 12);

#pragma unroll
    for (int w = 0; w < 3; ++w) {
        int row = tt + w - 1;
        if (row >= 0 && row < T_) {
            const float* hr = h1 + ((size_t)b * T_ + row) * DH;
            const float* kw = kk + w * DH * DC;
#pragma unroll 4
            for (int h4 = 0; h4 < 16; ++h4) {
                float4 hv = *reinterpret_cast<const float4*>(hr + h4 * 4);
#pragma unroll
                for (int u = 0; u < 4; ++u) {
                    float hvu = (u == 0) ? hv.x : (u == 1) ? hv.y : (u == 2) ? hv.z : hv.w;
                    const float4* kh = reinterpret_cast<const float4*>(kw + (h4 * 4 + u) * DC);
                    float4 k0 = kh[0], k1 = kh[1], k2 = kh[2], k3 = kh[3];
                    acc0.x = fmaf(hvu, k0.x, acc0.x); acc0.y = fmaf(hvu, k0.y, acc0.y);
                    acc0.z = fmaf(hvu, k0.z, acc0.z); acc0.w = fmaf(hvu, k0.w, acc0.w);
                    acc1.x = fmaf(hvu, k1.x, acc1.x); acc1.y = fmaf(hvu, k1.y, acc1.y);
                    acc1.z = fmaf(hvu, k1.z, acc1.z); acc1.w = fmaf(hvu, k1.w, acc1.w);
                    acc2.x = fmaf(hvu, k2.x, acc2.x); acc2.y = fmaf(hvu, k2.y, acc2.y);
                    acc2.z = fmaf(hvu, k2.z, acc2.z); acc2.w = fmaf(hvu, k2.w, acc2.w);
                    acc3.x = fmaf(hvu, k3.x, acc3.x); acc3.y = fmaf(hvu, k3.y, acc3.y);
                    acc3.z = fmaf(hvu, k3.z, acc3.z); acc3.w = fmaf(hvu, k3.w, acc3.w);
                }
            }
        }
    }
    // relu + projection to K=2
    float e0 = b2[0], e1 = b2[1];
    const float4* w2v = reinterpret_cast<const float4*>(W2);  // [2][16] -> 8 float4
    float4 hs[4];
    hs[0].x = fmaxf(acc0.x, 0.f); hs[0].y = fmaxf(acc0.y, 0.f); hs[0].z = fmaxf(acc0.z, 0.f); hs[0].w = fmaxf(acc0.w, 0.f);
    hs[1].x = fmaxf(acc1.x, 0.f); hs[1].y = fmaxf(acc1.y, 0.f); hs[1].z = fmaxf(acc1.z, 0.f); hs[1].w = fmaxf(acc1.w, 0.f);
    hs[2].x = fmaxf(acc2.x, 0.f); hs[2].y = fmaxf(acc2.y, 0.f); hs[2].z = fmaxf(acc2.z, 0.f); hs[2].w = fmaxf(acc2.w, 0.f);
    hs[3].x = fmaxf(acc3.x, 0.f); hs[3].y = fmaxf(acc3.y, 0.f); hs[3].z = fmaxf(acc3.z, 0.f); hs[3].w = fmaxf(acc3.w, 0.f);
#pragma unroll
    for (int c4 = 0; c4 < 4; ++c4) {
        float4 wa = w2v[c4], wb = w2v[4 + c4];
        e0 = fmaf(hs[c4].x, wa.x, e0); e0 = fmaf(hs[c4].y, wa.y, e0);
        e0 = fmaf(hs[c4].z, wa.z, e0); e0 = fmaf(hs[c4].w, wa.w, e0);
        e1 = fmaf(hs[c4].x, wb.x, e1); e1 = fmaf(hs[c4].y, wb.y, e1);
        e1 = fmaf(hs[c4].z, wb.z, e1); e1 = fmaf(hs[c4].w, wb.w, e1);
    }
    float2 o; o.x = e0; o.y = e1;
    *reinterpret_cast<float2*>(em + (size_t)tglob * 2) = o;
}

// ------------------------------------------------------------------
// K3 (fused): blocks 0-7 = CRF llh for batch b; blocks 8-15 = Viterbi
// for batch b-8.  CRF result atomicAdd'ed into outp[0] (zeroed by K2).
// ------------------------------------------------------------------
__device__ inline float lse2(float a, float b) {
    float m = fmaxf(a, b);
    float d = fabsf(a - b);
    return m + log1pf(__expf(-d));
}

__global__ __launch_bounds__(256) void k_crf_vit(const float* __restrict__ em,
                                                 const int* __restrict__ tokens_length,
                                                 const int* __restrict__ labels,
                                                 const float* __restrict__ startv,
                                                 const float* __restrict__ endv,
                                                 const float* __restrict__ transv,
                                                 float* __restrict__ outp) {
    __shared__ float em_s[T_ * 2];    // 32 KB, both paths
    __shared__ union {
        struct { int lab[T_]; float4 g4[256]; float red[4]; } c;                    // 20.02 KB
        struct { uint32_t bp[256]; uint32_t g[256]; uint8_t tag[T_]; int last; } v; // 6.1 KB
    } u;
    const int tid = threadIdx.x;
    const int b = blockIdx.x & 7;
    const int L = tokens_length[b];

    const float4* esrc = reinterpret_cast<const float4*>(em + (size_t)b * T_ * 2);
    for (int it = 0; it < 8; ++it)
        reinterpret_cast<float4*>(em_s)[it * 256 + tid] = esrc[it * 256 + tid];

    if (blockIdx.x < 8) {
        // ================= CRF path =================
        const int4* lsrc = reinterpret_cast<const int4*>(labels + (size_t)b * T_);
        for (int it = 0; it < 4; ++it)
            reinterpret_cast<int4*>(u.c.lab)[it * 256 + tid] = lsrc[it * 256 + tid];
        __syncthreads();

        float t00 = transv[0], t01 = transv[1], t10 = transv[2], t11 = transv[3];
        const int lo = tid * 16, hi = lo + 16;

        // numerator partial
        float nsum = 0.f;
        for (int t = (lo > 0 ? lo : 1); t < hi; ++t) {
            if (t < L) {
                int yt = u.c.lab[t], yp = u.c.lab[t - 1];
                float tr = yp ? (yt ? t11 : t10) : (yt ? t01 : t00);
                nsum += em_s[2 * t + yt] + tr;
            }
        }
        if (tid == 0) {
            int y0 = u.c.lab[0];
            nsum += startv[y0] + em_s[y0];
            nsum += endv[u.c.lab[L - 1]];
        }
        for (int o = 32; o > 0; o >>= 1) nsum += __shfl_down(nsum, o);
        if ((tid & 63) == 0) u.c.red[tid >> 6] = nsum;

        // denominator: per-thread chunk of 2x2 log-semiring products
        float G00 = 0.f, G01 = -1e30f, G10 = -1e30f, G11 = 0.f;
        for (int t = (lo > 0 ? lo : 1); t < hi; ++t) {
            if (t < L) {
                float e0 = em_s[2 * t], e1 = em_s[2 * t + 1];
                float n00 = lse2(G00 + t00, G01 + t10) + e0;
                float n01 = lse2(G00 + t01, G01 + t11) + e1;
                float n10 = lse2(G10 + t00, G11 + t10) + e0;
                float n11 = lse2(G10 + t01, G11 + t11) + e1;
                G00 = n00; G01 = n01; G10 = n10; G11 = n11;
            }
        }
        u.c.g4[tid] = make_float4(G00, G01, G10, G11);
        __syncthreads();
        for (int s2 = 1; s2 < 256; s2 <<= 1) {
            bool act = ((tid & (2 * s2 - 1)) == 0);
            float4 gg = make_float4(0.f, 0.f, 0.f, 0.f);
            if (act) {
                float4 a = u.c.g4[tid], c = u.c.g4[tid + s2];
                gg.x = lse2(a.x + c.x, a.y + c.z);
                gg.y = lse2(a.x + c.y, a.y + c.w);
                gg.z = lse2(a.z + c.x, a.w + c.z);
                gg.w = lse2(a.z + c.y, a.w + c.w);
            }
            __syncthreads();
            if (act) u.c.g4[tid] = gg;
            __syncthreads();
        }
        if (tid == 0) {
            float4 G = u.c.g4[0];
            float s0 = startv[0] + em_s[0], s1 = startv[1] + em_s[1];
            float f0 = lse2(s0 + G.x, s1 + G.z);
            float f1 = lse2(s0 + G.y, s1 + G.w);
            float denom = lse2(f0 + endv[0], f1 + endv[1]);
            float num = u.c.red[0] + u.c.red[1] + u.c.red[2] + u.c.red[3];
            atomicAdd(outp, denom - num);
        }
    } else {
        // ================= Viterbi path =================
        __syncthreads();

        if (tid == 0) {
            const float t00 = transv[0], t01 = transv[1], t10 = transv[2], t11 = transv[3];
            float s0 = startv[0] + em_s[0];
            float s1 = startv[1] + em_s[1];
            uint32_t word = 2u;   // t=0 slot = identity
            int bitpos = 2, wi = 0, t = 1;
            for (; t < L; ++t) {
                float c00 = s0 + t00, c10 = s1 + t10;
                float c01 = s0 + t01, c11 = s1 + t11;
                uint32_t bits = (c10 > c00 ? 1u : 0u) | (c11 > c01 ? 2u : 0u);
                s0 = fmaxf(c00, c10) + em_s[2 * t];
                s1 = fmaxf(c01, c11) + em_s[2 * t + 1];
                word |= bits << bitpos;
                bitpos += 2;
                if (bitpos == 32) { u.v.bp[wi++] = word; word = 0; bitpos = 0; }
            }
            // fill identity up to word boundary, then bulk identity words
            for (; t < T_ && bitpos != 0; ++t) {
                word |= 2u << bitpos;
                bitpos += 2;
                if (bitpos == 32) { u.v.bp[wi++] = word; word = 0; bitpos = 0; }
            }
            for (; wi < 256; ++wi) u.v.bp[wi] = 0xAAAAAAAAu;
            u.v.last = (s1 + endv[1] > s0 + endv[0]) ? 1 : 0;
        }
        __syncthreads();

        // per-thread 16-step map composition: g = f_{16T} o ... o f_{16T+15}
        uint32_t w = u.v.bp[tid];
        uint32_t g0 = 0u, g1 = 1u;
#pragma unroll
        for (int r = 15; r >= 0; --r) {
            uint32_t bits = (w >> (2 * r)) & 3u;
            uint32_t f0 = bits & 1u, f1 = bits >> 1;
            uint32_t n0 = g0 ? f1 : f0;
            uint32_t n1 = g1 ? f1 : f0;
            g0 = n0; g1 = n1;
        }
        u.v.g[tid] = g0 | (g1 << 1);
        __syncthreads();
        // suffix scan: g[tid] = g_tid o g_{tid+1} o ... o g_255
        for (int s2 = 1; s2 < 256; s2 <<= 1) {
            uint32_t a = u.v.g[tid];
            uint32_t bw = (tid + s2 < 256) ? u.v.g[tid + s2] : 2u;
            __syncthreads();
            uint32_t b0 = bw & 1u, b1 = (bw >> 1) & 1u;
            u.v.g[tid] = ((a >> b0) & 1u) | (((a >> b1) & 1u) << 1);
            __syncthreads();
        }
        int last = u.v.last;
        uint32_t suff = (tid < 255) ? u.v.g[tid + 1] : 2u;
        int cur = (int)((suff >> last) & 1u);
        // replay: out[16*tid + r] = cur; cur = f_{16*tid+r}(cur)
        int base = tid * 16;
#pragma unroll
        for (int r = 15; r >= 0; --r) {
            u.v.tag[base + r] = (uint8_t)cur;
            cur = (int)((w >> (2 * r + cur)) & 1u);
        }
        __syncthreads();
        for (int it = 0; it < 16; ++it) {
            int idx = it * 256 + tid;
            outp[1 + (size_t)b * T_ + idx] = (float)u.v.tag[idx];
        }
    }
}

// ------------------------------------------------------------------
extern "C" void kernel_launch(void* const* d_in, const int* in_sizes, int n_in,
                              void* d_out, int out_size, void* d_ws, size_t ws_size,
                              hipStream_t stream) {
    const float* x      = (const float*)d_in[0];
    const int*   toklen = (const int*)d_in[1];
    const int*   labels = (const int*)d_in[2];
    const float* W1     = (const float*)d_in[3];
    const float* b1     = (const float*)d_in[4];
    const float* Wc     = (const float*)d_in[5];
    const float* bc     = (const float*)d_in[6];
    const float* W2     = (const float*)d_in[7];
    const float* b2     = (const float*)d_in[8];
    const float* startv = (const float*)d_in[9];
    const float* endv   = (const float*)d_in[10];
    const float* transv = (const float*)d_in[11];
    float* outp = (float*)d_out;
    float* ws   = (float*)d_ws;

    float* w1t = ws + OFF_W1T;
    float* h1  = ws + OFF_H1;
    float* em  = ws + OFF_EM;

    k_transpose_w1<<<dim3((DINP * DH + 255) / 256), dim3(256), 0, stream>>>(W1, w1t);
    k_gemm1<<<dim3(M_ / MT), dim3(256), 0, stream>>>(x, w1t, b1, h1);
    k_conv_em<<<dim3(M_ / 256), dim3(256), 0, stream>>>(h1, Wc, bc, W2, b2, em, outp);
    k_crf_vit<<<dim3(16), dim3(256), 0, stream>>>(em, toklen, labels, startv, endv, transv, outp);
}

// Round 3
// 438.064 us; speedup vs baseline: 1.4411x; 1.4411x over previous
//
#include <hip/hip_runtime.h>
#include <stdint.h>

#define B_   8
#define T_   4096
#define DIN  1330
#define DH   64
#define DC   16
#define KK   2
#define M_   (B_*T_)       // 32768
#define DINP 1344          // 42*32, zero-padded K for W1^T

// ---- workspace layout (floats) ----
#define OFF_W1T 0
#define OFF_H1  (DINP*DH)                 // 86016
#define OFF_EM  (OFF_H1 + M_*DH)          // + 2097152
#define WS_FLOATS (OFF_EM + M_*KK)

// ------------------------------------------------------------------
// K0: W1 (64 x 1330) -> W1T (1344 x 64), zero-padded rows >= 1330
// ------------------------------------------------------------------
__global__ void k_transpose_w1(const float* __restrict__ W1, float* __restrict__ w1t) {
    int idx = blockIdx.x * 256 + threadIdx.x;
    if (idx >= DINP * DH) return;
    int d = idx >> 6, h = idx & 63;
    w1t[idx] = (d < DIN) ? W1[h * DIN + d] : 0.f;
}

// ------------------------------------------------------------------
// K1: h1 = relu(x @ W1^T + b1)   (32768 x 1330) x (1330 x 64)
// ------------------------------------------------------------------
#define MT 64
#define KC 32
__global__ __launch_bounds__(256) void k_gemm1(const float* __restrict__ x,
                                               const float* __restrict__ w1t,
                                               const float* __restrict__ b1,
                                               float* __restrict__ h1) {
    __shared__ float As[MT * 36];      // 9216 B
    __shared__ float Bs[KC * DH];      // 8192 B
    const int tid  = threadIdx.x;
    const int row0 = blockIdx.x * MT;
    const int jm = tid & 15, jh = tid >> 4;
    const int m0 = jm * 4, h0 = jh * 4;
    const int s_rd = jm >> 1;          // == ((m0+i)>>3)&7 for i in 0..3

    float4 acc[4];
#pragma unroll
    for (int i = 0; i < 4; ++i) acc[i] = make_float4(0.f, 0.f, 0.f, 0.f);

    const int NCH = DINP / KC;  // 42
    for (int ch = 0; ch < NCH; ++ch) {
        const int kc = ch * KC;
        // ---- stage B: Bs[k][h] = w1t[(kc+k)*64 + h], 2048 floats ----
#pragma unroll
        for (int it = 0; it < 2; ++it) {
            int p = it * 256 + tid;
            reinterpret_cast<float4*>(Bs)[p] =
                reinterpret_cast<const float4*>(w1t + (size_t)kc * DH)[p];
        }
        // ---- stage A (swizzled) ----
        if (ch < NCH - 1) {
#pragma unroll
            for (int it = 0; it < 4; ++it) {
                int P = it * 256 + tid;          // pair index [0,1024)
                int m = P >> 4, kp = P & 15;     // k = 2*kp
                float2 v = *reinterpret_cast<const float2*>(
                    x + (size_t)(row0 + m) * DIN + kc + kp * 2);
                int s = (m >> 3) & 7;
                int slot = m * 36 + 4 * ((kp >> 1) ^ s) + 2 * (kp & 1);
                *reinterpret_cast<float2*>(As + slot) = v;
            }
        } else {
            // tail: only k < 1330 valid, zero-fill the rest
            for (int idx = tid; idx < MT * KC; idx += 256) {
                int m = idx >> 5, k = idx & 31;
                float v = (kc + k < DIN) ? x[(size_t)(row0 + m) * DIN + kc + k] : 0.f;
                int s = (m >> 3) & 7;
                As[m * 36 + 4 * ((k >> 2) ^ s) + (k & 3)] = v;
            }
        }
        __syncthreads();
        // ---- compute ----
#pragma unroll
        for (int kq = 0; kq < 8; ++kq) {
            float4 bv0 = *reinterpret_cast<const float4*>(Bs + (kq * 4 + 0) * DH + h0);
            float4 bv1 = *reinterpret_cast<const float4*>(Bs + (kq * 4 + 1) * DH + h0);
            float4 bv2 = *reinterpret_cast<const float4*>(Bs + (kq * 4 + 2) * DH + h0);
            float4 bv3 = *reinterpret_cast<const float4*>(Bs + (kq * 4 + 3) * DH + h0);
            const int xo = 4 * (kq ^ s_rd);
#pragma unroll
            for (int i = 0; i < 4; ++i) {
                const float4 av = *reinterpret_cast<const float4*>(As + (m0 + i) * 36 + xo);
                acc[i].x = fmaf(av.x, bv0.x, acc[i].x);
                acc[i].y = fmaf(av.x, bv0.y, acc[i].y);
                acc[i].z = fmaf(av.x, bv0.z, acc[i].z);
                acc[i].w = fmaf(av.x, bv0.w, acc[i].w);
                acc[i].x = fmaf(av.y, bv1.x, acc[i].x);
                acc[i].y = fmaf(av.y, bv1.y, acc[i].y);
                acc[i].z = fmaf(av.y, bv1.z, acc[i].z);
                acc[i].w = fmaf(av.y, bv1.w, acc[i].w);
                acc[i].x = fmaf(av.z, bv2.x, acc[i].x);
                acc[i].y = fmaf(av.z, bv2.y, acc[i].y);
                acc[i].z = fmaf(av.z, bv2.z, acc[i].z);
                acc[i].w = fmaf(av.z, bv2.w, acc[i].w);
                acc[i].x = fmaf(av.w, bv3.x, acc[i].x);
                acc[i].y = fmaf(av.w, bv3.y, acc[i].y);
                acc[i].z = fmaf(av.w, bv3.z, acc[i].z);
                acc[i].w = fmaf(av.w, bv3.w, acc[i].w);
            }
        }
        __syncthreads();
    }
    // epilogue: + b1, relu, store
    float4 bb = *reinterpret_cast<const float4*>(b1 + h0);
#pragma unroll
    for (int i = 0; i < 4; ++i) {
        float4 o;
        o.x = fmaxf(acc[i].x + bb.x, 0.f);
        o.y = fmaxf(acc[i].y + bb.y, 0.f);
        o.z = fmaxf(acc[i].z + bb.z, 0.f);
        o.w = fmaxf(acc[i].w + bb.w, 0.f);
        *reinterpret_cast<float4*>(h1 + (size_t)(row0 + m0 + i) * DH + h0) = o;
    }
}

// ------------------------------------------------------------------
// K2: em = relu(conv1d(h1, Wc, pad=1) + bc) @ W2^T + b2
// Also zeroes outp[0] so the CRF kernel can atomicAdd into it.
// ------------------------------------------------------------------
__global__ __launch_bounds__(256) void k_conv_em(const float* __restrict__ h1,
                                                 const float* __restrict__ Wc,
                                                 const float* __restrict__ bc,
                                                 const float* __restrict__ W2,
                                                 const float* __restrict__ b2,
                                                 float* __restrict__ em,
                                                 float* __restrict__ outp) {
    __shared__ float kk[3 * DH * DC];  // 12 KB: kk[w][h][c] = Wc[c][h][w]
    int tid = threadIdx.x;
    if (blockIdx.x == 0 && tid == 0) outp[0] = 0.f;
    for (int idx = tid; idx < 3 * DH * DC; idx += 256) {
        int w = idx / (DH * DC);
        int rem = idx - w * DH * DC;
        int h = rem >> 4, c = rem & 15;
        kk[idx] = Wc[(c * DH + h) * 3 + w];
    }
    __syncthreads();
    int tglob = blockIdx.x * 256 + tid;   // [0, 32768)
    int b = tglob >> 12, tt = tglob & 4095;

    float4 acc0 = *reinterpret_cast<const float4*>(bc + 0);
    float4 acc1 = *reinterpret_cast<const float4*>(bc + 4);
    float4 acc2 = *reinterpret_cast<const float4*>(bc + 8);
    float4 acc3 = *reinterpret_cast<const float4*>(bc + 12);

#pragma unroll
    for (int w = 0; w < 3; ++w) {
        int row = tt + w - 1;
        if (row >= 0 && row < T_) {
            const float* hr = h1 + ((size_t)b * T_ + row) * DH;
            const float* kw = kk + w * DH * DC;
#pragma unroll 4
            for (int h4 = 0; h4 < 16; ++h4) {
                float4 hv = *reinterpret_cast<const float4*>(hr + h4 * 4);
#pragma unroll
                for (int u = 0; u < 4; ++u) {
                    float hvu = (u == 0) ? hv.x : (u == 1) ? hv.y : (u == 2) ? hv.z : hv.w;
                    const float4* kh = reinterpret_cast<const float4*>(kw + (h4 * 4 + u) * DC);
                    float4 k0 = kh[0], k1 = kh[1], k2 = kh[2], k3 = kh[3];
                    acc0.x = fmaf(hvu, k0.x, acc0.x); acc0.y = fmaf(hvu, k0.y, acc0.y);
                    acc0.z = fmaf(hvu, k0.z, acc0.z); acc0.w = fmaf(hvu, k0.w, acc0.w);
                    acc1.x = fmaf(hvu, k1.x, acc1.x); acc1.y = fmaf(hvu, k1.y, acc1.y);
                    acc1.z = fmaf(hvu, k1.z, acc1.z); acc1.w = fmaf(hvu, k1.w, acc1.w);
                    acc2.x = fmaf(hvu, k2.x, acc2.x); acc2.y = fmaf(hvu, k2.y, acc2.y);
                    acc2.z = fmaf(hvu, k2.z, acc2.z); acc2.w = fmaf(hvu, k2.w, acc2.w);
                    acc3.x = fmaf(hvu, k3.x, acc3.x); acc3.y = fmaf(hvu, k3.y, acc3.y);
                    acc3.z = fmaf(hvu, k3.z, acc3.z); acc3.w = fmaf(hvu, k3.w, acc3.w);
                }
            }
        }
    }
    // relu + projection to K=2
    float e0 = b2[0], e1 = b2[1];
    const float4* w2v = reinterpret_cast<const float4*>(W2);  // [2][16] -> 8 float4
    float4 hs[4];
    hs[0].x = fmaxf(acc0.x, 0.f); hs[0].y = fmaxf(acc0.y, 0.f); hs[0].z = fmaxf(acc0.z, 0.f); hs[0].w = fmaxf(acc0.w, 0.f);
    hs[1].x = fmaxf(acc1.x, 0.f); hs[1].y = fmaxf(acc1.y, 0.f); hs[1].z = fmaxf(acc1.z, 0.f); hs[1].w = fmaxf(acc1.w, 0.f);
    hs[2].x = fmaxf(acc2.x, 0.f); hs[2].y = fmaxf(acc2.y, 0.f); hs[2].z = fmaxf(acc2.z, 0.f); hs[2].w = fmaxf(acc2.w, 0.f);
    hs[3].x = fmaxf(acc3.x, 0.f); hs[3].y = fmaxf(acc3.y, 0.f); hs[3].z = fmaxf(acc3.z, 0.f); hs[3].w = fmaxf(acc3.w, 0.f);
#pragma unroll
    for (int c4 = 0; c4 < 4; ++c4) {
        float4 wa = w2v[c4], wb = w2v[4 + c4];
        e0 = fmaf(hs[c4].x, wa.x, e0); e0 = fmaf(hs[c4].y, wa.y, e0);
        e0 = fmaf(hs[c4].z, wa.z, e0); e0 = fmaf(hs[c4].w, wa.w, e0);
        e1 = fmaf(hs[c4].x, wb.x, e1); e1 = fmaf(hs[c4].y, wb.y, e1);
        e1 = fmaf(hs[c4].z, wb.z, e1); e1 = fmaf(hs[c4].w, wb.w, e1);
    }
    float2 o; o.x = e0; o.y = e1;
    *reinterpret_cast<float2*>(em + (size_t)tglob * 2) = o;
}

// ------------------------------------------------------------------
// K3 (fused): blocks 0-7 = CRF llh (atomicAdd into outp[0]);
// blocks 8-15 = Viterbi (two-pass: serial scores + parallel bits).
// ------------------------------------------------------------------
__device__ inline float lse2(float a, float b) {
    float m = fmaxf(a, b);
    float d = fabsf(a - b);
    return m + __logf(1.f + __expf(-d));   // hw v_exp + v_log; err ~1e-6, thr 217
}

// prefetch 16 steps (32 floats) of em into a register buffer
#define VIT_PREFETCH(EBUF, BIDX) do {                                          \
    int pb_ = (BIDX); if (pb_ > 255) pb_ = 255;                                \
    _Pragma("unroll")                                                          \
    for (int q = 0; q < 8; ++q) {                                              \
        float4 v_ = ev[8 * pb_ + q];                                           \
        EBUF[4*q] = v_.x; EBUF[4*q+1] = v_.y; EBUF[4*q+2] = v_.z; EBUF[4*q+3] = v_.w; \
    }                                                                          \
} while (0)

// 16 serial score steps from register buffer; writes score to LDS
#define VIT_STEPS(EBUF, BB, R0) do {                                           \
    _Pragma("unroll")                                                          \
    for (int r = (R0); r < 16; ++r) {                                          \
        float c00 = s0 + t00, c10 = s1 + t10;                                  \
        float c01 = s0 + t01, c11 = s1 + t11;                                  \
        s0 = fmaxf(c00, c10) + EBUF[2*r];                                      \
        s1 = fmaxf(c01, c11) + EBUF[2*r+1];                                    \
        sc[((BB) << 4) + r] = make_float2(s0, s1);                             \
    }                                                                          \
} while (0)

__global__ __launch_bounds__(256) void k_crf_vit(const float* __restrict__ em,
                                                 const int* __restrict__ tokens_length,
                                                 const int* __restrict__ labels,
                                                 const float* __restrict__ startv,
                                                 const float* __restrict__ endv,
                                                 const float* __restrict__ transv,
                                                 float* __restrict__ outp) {
    __shared__ float em_s[T_ * 2];    // 32 KB, both paths
    __shared__ union {
        struct { int lab[T_]; float4 g4[256]; float red[4]; } c;                     // 20.02 KB
        struct { float2 score[T_]; uint32_t g[256]; uint8_t tag[T_]; int last; } v;  // 37.9 KB
    } u;
    const int tid = threadIdx.x;
    const int b = blockIdx.x & 7;
    const int L = tokens_length[b];

    const float4* esrc = reinterpret_cast<const float4*>(em + (size_t)b * T_ * 2);
    for (int it = 0; it < 8; ++it)
        reinterpret_cast<float4*>(em_s)[it * 256 + tid] = esrc[it * 256 + tid];

    const float t00 = transv[0], t01 = transv[1], t10 = transv[2], t11 = transv[3];

    if (blockIdx.x < 8) {
        // ================= CRF path =================
        const int4* lsrc = reinterpret_cast<const int4*>(labels + (size_t)b * T_);
        for (int it = 0; it < 4; ++it)
            reinterpret_cast<int4*>(u.c.lab)[it * 256 + tid] = lsrc[it * 256 + tid];
        __syncthreads();

        const int lo = tid * 16, hi = lo + 16;

        // numerator partial
        float nsum = 0.f;
        for (int t = (lo > 0 ? lo : 1); t < hi; ++t) {
            if (t < L) {
                int yt = u.c.lab[t], yp = u.c.lab[t - 1];
                float tr = yp ? (yt ? t11 : t10) : (yt ? t01 : t00);
                nsum += em_s[2 * t + yt] + tr;
            }
        }
        if (tid == 0) {
            int y0 = u.c.lab[0];
            nsum += startv[y0] + em_s[y0];
            nsum += endv[u.c.lab[L - 1]];
        }
        for (int o = 32; o > 0; o >>= 1) nsum += __shfl_down(nsum, o);
        if ((tid & 63) == 0) u.c.red[tid >> 6] = nsum;

        // denominator: per-thread chunk of 2x2 log-semiring products
        float G00 = 0.f, G01 = -1e30f, G10 = -1e30f, G11 = 0.f;
        for (int t = (lo > 0 ? lo : 1); t < hi; ++t) {
            if (t < L) {
                float e0 = em_s[2 * t], e1 = em_s[2 * t + 1];
                float n00 = lse2(G00 + t00, G01 + t10) + e0;
                float n01 = lse2(G00 + t01, G01 + t11) + e1;
                float n10 = lse2(G10 + t00, G11 + t10) + e0;
                float n11 = lse2(G10 + t01, G11 + t11) + e1;
                G00 = n00; G01 = n01; G10 = n10; G11 = n11;
            }
        }
        u.c.g4[tid] = make_float4(G00, G01, G10, G11);
        __syncthreads();
        for (int s2 = 1; s2 < 256; s2 <<= 1) {
            bool act = ((tid & (2 * s2 - 1)) == 0);
            float4 gg = make_float4(0.f, 0.f, 0.f, 0.f);
            if (act) {
                float4 a = u.c.g4[tid], c = u.c.g4[tid + s2];
                gg.x = lse2(a.x + c.x, a.y + c.z);
                gg.y = lse2(a.x + c.y, a.y + c.w);
                gg.z = lse2(a.z + c.x, a.w + c.z);
                gg.w = lse2(a.z + c.y, a.w + c.w);
            }
            __syncthreads();
            if (act) u.c.g4[tid] = gg;
            __syncthreads();
        }
        if (tid == 0) {
            float4 G = u.c.g4[0];
            float s0 = startv[0] + em_s[0], s1 = startv[1] + em_s[1];
            float f0 = lse2(s0 + G.x, s1 + G.z);
            float f1 = lse2(s0 + G.y, s1 + G.w);
            float denom = lse2(f0 + endv[0], f1 + endv[1]);
            float num = u.c.red[0] + u.c.red[1] + u.c.red[2] + u.c.red[3];
            atomicAdd(outp, denom - num);
        }
    } else {
        // ================= Viterbi path =================
        __syncthreads();   // em_s staged
        float2* sc = u.v.score;

        // ---- pass 1: serial scores (tid 0), em prefetched 16 steps ahead ----
        if (tid == 0) {
            float s0 = startv[0] + em_s[0];
            float s1 = startv[1] + em_s[1];
            sc[0] = make_float2(s0, s1);
            const float4* ev = reinterpret_cast<const float4*>(em_s);
            float ea[32], eb[32];
            const int nfull = L >> 4;   // blocks with all 16 t's < L
            int blk;
            if (nfull > 0) {
                VIT_PREFETCH(ea, 0);
                VIT_PREFETCH(eb, 1);
                VIT_STEPS(ea, 0, 1);    // t = 1..15
                blk = 1;
                for (; blk + 1 < nfull; blk += 2) {
                    VIT_PREFETCH(ea, blk + 1);
                    VIT_STEPS(eb, blk, 0);
                    VIT_PREFETCH(eb, blk + 2);
                    VIT_STEPS(ea, blk + 1, 0);
                }
                if (blk < nfull) {      // one leftover full block, data in eb
                    VIT_STEPS(eb, blk, 0);
                    ++blk;
                }
            } else {
                blk = 0;
            }
            // tail: t in [max(16*blk,1), L)
            {
                const float2* e2 = reinterpret_cast<const float2*>(em_s);
                int t = blk << 4;
                if (t == 0) t = 1;
                for (; t < L; ++t) {
                    float2 e = e2[t];
                    float c00 = s0 + t00, c10 = s1 + t10;
                    float c01 = s0 + t01, c11 = s1 + t11;
                    s0 = fmaxf(c00, c10) + e.x;
                    s1 = fmaxf(c01, c11) + e.y;
                    sc[t] = make_float2(s0, s1);
                }
            }
            u.v.last = (s1 + endv[1] > s0 + endv[0]) ? 1 : 0;
        }
        __syncthreads();

        // ---- pass 2: parallel backpointer extraction from stored scores ----
        const int t0w = tid << 4;
        uint32_t w = 0;
#pragma unroll
        for (int r = 0; r < 16; ++r) {
            int t = t0w + r;
            uint32_t bits = 2u;                 // identity (t==0 or t>=L)
            if (t > 0 && t < L) {
                float2 ps = sc[t - 1];
                float c00 = ps.x + t00, c10 = ps.y + t10;
                float c01 = ps.x + t01, c11 = ps.y + t11;
                bits = (c10 > c00 ? 1u : 0u) | (c11 > c01 ? 2u : 0u);
            }
            w |= bits << (2 * r);
        }

        // ---- map composition: g = f_{16T} o ... o f_{16T+15} ----
        uint32_t g0 = 0u, g1 = 1u;
#pragma unroll
        for (int r = 15; r >= 0; --r) {
            uint32_t bits = (w >> (2 * r)) & 3u;
            uint32_t f0 = bits & 1u, f1 = bits >> 1;
            uint32_t n0 = g0 ? f1 : f0;
            uint32_t n1 = g1 ? f1 : f0;
            g0 = n0; g1 = n1;
        }
        u.v.g[tid] = g0 | (g1 << 1);
        __syncthreads();
        // suffix scan: g[tid] = g_tid o g_{tid+1} o ... o g_255
        for (int s2 = 1; s2 < 256; s2 <<= 1) {
            uint32_t a = u.v.g[tid];
            uint32_t bw = (tid + s2 < 256) ? u.v.g[tid + s2] : 2u;
            __syncthreads();
            uint32_t b0 = bw & 1u, b1 = (bw >> 1) & 1u;
            u.v.g[tid] = ((a >> b0) & 1u) | (((a >> b1) & 1u) << 1);
            __syncthreads();
        }
        int last = u.v.last;
        uint32_t suff = (tid < 255) ? u.v.g[tid + 1] : 2u;
        int cur = (int)((suff >> last) & 1u);
        // replay: tag[16*tid + r] = cur; cur = f_{16*tid+r}(cur)
        int base = tid * 16;
#pragma unroll
        for (int r = 15; r >= 0; --r) {
            u.v.tag[base + r] = (uint8_t)cur;
            cur = (int)((w >> (2 * r + cur)) & 1u);
        }
        __syncthreads();
        for (int it = 0; it < 16; ++it) {
            int idx = it * 256 + tid;
            outp[1 + (size_t)b * T_ + idx] = (float)u.v.tag[idx];
        }
    }
}

// ------------------------------------------------------------------
extern "C" void kernel_launch(void* const* d_in, const int* in_sizes, int n_in,
                              void* d_out, int out_size, void* d_ws, size_t ws_size,
                              hipStream_t stream) {
    const float* x      = (const float*)d_in[0];
    const int*   toklen = (const int*)d_in[1];
    const int*   labels = (const int*)d_in[2];
    const float* W1     = (const float*)d_in[3];
    const float* b1     = (const float*)d_in[4];
    const float* Wc     = (const float*)d_in[5];
    const float* bc     = (const float*)d_in[6];
    const float* W2     = (const float*)d_in[7];
    const float* b2     = (const float*)d_in[8];
    const float* startv = (const float*)d_in[9];
    const float* endv   = (const float*)d_in[10];
    const float* transv = (const float*)d_in[11];
    float* outp = (float*)d_out;
    float* ws   = (float*)d_ws;

    float* w1t = ws + OFF_W1T;
    float* h1  = ws + OFF_H1;
    float* em  = ws + OFF_EM;

    k_transpose_w1<<<dim3((DINP * DH + 255) / 256), dim3(256), 0, stream>>>(W1, w1t);
    k_gemm1<<<dim3(M_ / MT), dim3(256), 0, stream>>>(x, w1t, b1, h1);
    k_conv_em<<<dim3(M_ / 256), dim3(256), 0, stream>>>(h1, Wc, bc, W2, b2, em, outp);
    k_crf_vit<<<dim3(16), dim3(256), 0, stream>>>(em, toklen, labels, startv, endv, transv, outp);
}